// Round 1
// baseline (478.522 us; speedup 1.0000x reference)
//
#include <hip/hip_runtime.h>
#include <math.h>

#define NN    50000
#define NE0   800000
#define NE    850000
#define INDIM 128
#define HID   64
#define OUTD  40

// ---------------------------------------------------------------- CSR build
__global__ void k_zero_deg(int* __restrict__ deg) {
    int i = blockIdx.x * 256 + threadIdx.x;
    if (i < NN) deg[i] = 0;
}

__global__ void k_deg(const int* __restrict__ ei, int* __restrict__ deg) {
    int e = blockIdx.x * 256 + threadIdx.x;
    if (e >= NE) return;
    int dst = (e < NE0) ? ei[NE0 + e] : (e - NE0);
    atomicAdd(&deg[dst], 1);
}

// single-block exclusive scan over NN degrees -> off[0..NN], cursor copy
__global__ __launch_bounds__(1024) void k_scan(const int* __restrict__ deg,
                                               int* __restrict__ off,
                                               int* __restrict__ cur) {
    __shared__ int buf[1024];
    __shared__ int s_run;
    const int tid = threadIdx.x;
    if (tid == 0) s_run = 0;
    __syncthreads();
    for (int base = 0; base < NN; base += 1024) {
        int i = base + tid;
        int v = (i < NN) ? deg[i] : 0;
        __syncthreads();               // protect prev iter's buf[1023] read
        buf[tid] = v;
        __syncthreads();
        int incl = v;
        for (int s = 1; s < 1024; s <<= 1) {
            int t = (tid >= s) ? buf[tid - s] : 0;
            __syncthreads();
            incl += t;
            buf[tid] = incl;
            __syncthreads();
        }
        int run = s_run;
        if (i < NN) {
            int ex = run + incl - v;
            off[i] = ex;
            cur[i] = ex;
        }
        __syncthreads();               // all reads of s_run done
        if (tid == 0) s_run = run + buf[1023];
    }
    if (tid == 0) off[NN] = NE;
}

__global__ void k_scatter(const int* __restrict__ ei, int* __restrict__ cur,
                          int* __restrict__ esrc) {
    int e = blockIdx.x * 256 + threadIdx.x;
    if (e >= NE) return;
    int src, dst;
    if (e < NE0) { src = ei[e]; dst = ei[NE0 + e]; }
    else         { src = e - NE0; dst = src; }
    int pos = atomicAdd(&cur[dst], 1);
    esrc[pos] = src;
}

// ---------------------------------------------------------------- GEMM1: x(50000x128) @ W1(128x64) + alpha logits
__global__ __launch_bounds__(256) void k_gemm1(
    const float* __restrict__ x, const float* __restrict__ W1,
    const float* __restrict__ a_s, const float* __restrict__ a_d,
    float* __restrict__ h1, float* __restrict__ asrc1, float* __restrict__ adst1)
{
    __shared__ float Wl[INDIM * HID];      // 32 KB
    __shared__ float xs[16 * 132];         // padded stride 132
    const int tid = threadIdx.x;
    const int r0 = blockIdx.x * 16;

    const float4* W4 = (const float4*)W1;
    float4* Wl4 = (float4*)Wl;
#pragma unroll
    for (int i = 0; i < 8; ++i) Wl4[tid + i * 256] = W4[tid + i * 256];

    const float4* x4 = (const float4*)x;
#pragma unroll
    for (int i = 0; i < 2; ++i) {
        int idx = tid + i * 256;           // 0..511
        int row = idx >> 5;                // 32 float4 per row
        int k4  = idx & 31;
        float4 v = x4[(size_t)(r0 + row) * 32 + k4];
        *(float4*)&xs[row * 132 + k4 * 4] = v;
    }
    __syncthreads();

    const int r  = tid >> 4;               // 0..15
    const int c4 = (tid & 15) * 4;         // 0,4,...,60
    float a0 = 0.f, a1 = 0.f, a2 = 0.f, a3 = 0.f;
#pragma unroll 8
    for (int k4 = 0; k4 < 32; ++k4) {
        float4 xv = *(const float4*)&xs[r * 132 + k4 * 4];
        const float* wp = &Wl[(k4 * 4) * HID + c4];
        float4 w0 = *(const float4*)(wp);
        float4 w1 = *(const float4*)(wp + HID);
        float4 w2 = *(const float4*)(wp + 2 * HID);
        float4 w3 = *(const float4*)(wp + 3 * HID);
        a0 += xv.x * w0.x + xv.y * w1.x + xv.z * w2.x + xv.w * w3.x;
        a1 += xv.x * w0.y + xv.y * w1.y + xv.z * w2.y + xv.w * w3.y;
        a2 += xv.x * w0.z + xv.y * w1.z + xv.z * w2.z + xv.w * w3.z;
        a3 += xv.x * w0.w + xv.y * w1.w + xv.z * w2.w + xv.w * w3.w;
    }
    const int n = r0 + r;
    float4 hv; hv.x = a0; hv.y = a1; hv.z = a2; hv.w = a3;
    *(float4*)&h1[(size_t)n * HID + c4] = hv;

    // fused per-node attention logits: reduce 4 lanes (same row, same head)
    float ps = a0 * a_s[c4] + a1 * a_s[c4 + 1] + a2 * a_s[c4 + 2] + a3 * a_s[c4 + 3];
    float pd = a0 * a_d[c4] + a1 * a_d[c4 + 1] + a2 * a_d[c4 + 2] + a3 * a_d[c4 + 3];
    ps += __shfl_xor(ps, 1); ps += __shfl_xor(ps, 2);
    pd += __shfl_xor(pd, 1); pd += __shfl_xor(pd, 2);
    int cg = tid & 15;
    if ((cg & 3) == 0) {
        int head = cg >> 2;
        asrc1[n * 4 + head] = ps;
        adst1[n * 4 + head] = pd;
    }
}

// ---------------------------------------------------------------- layer-1 aggregate (online softmax), + bias + relu
__global__ __launch_bounds__(256) void k_agg1(
    const int* __restrict__ off, const int* __restrict__ esrc,
    const float* __restrict__ h1, const float* __restrict__ asrc1,
    const float* __restrict__ adst1, const float* __restrict__ b1,
    float* __restrict__ hmid)
{
    const int wave = threadIdx.x >> 6;
    const int lane = threadIdx.x & 63;
    const int n = blockIdx.x * 4 + wave;
    if (n >= NN) return;
    const int head = lane >> 4;
    const int s0 = off[n], s1 = off[n + 1];
    const float adst = adst1[n * 4 + head];
    float m = -INFINITY, l = 0.f, acc = 0.f;
    for (int idx = s0; idx < s1; ++idx) {
        int s = esrc[idx];
        float e = asrc1[s * 4 + head] + adst;
        e = (e > 0.f) ? e : 0.2f * e;
        float mn = fmaxf(m, e);
        float p = __expf(e - mn);
        float sc = __expf(m - mn);
        float hv = h1[(size_t)s * HID + lane];
        l = l * sc + p;
        acc = acc * sc + p * hv;
        m = mn;
    }
    float val = acc / l + b1[lane];
    hmid[(size_t)n * HID + lane] = fmaxf(val, 0.f);
}

// ---------------------------------------------------------------- GEMM2: hmid(50000x64) @ W2(64x40) + alpha logits
__global__ __launch_bounds__(320) void k_gemm2(
    const float* __restrict__ hin, const float* __restrict__ W2,
    const float* __restrict__ a_s, const float* __restrict__ a_d,
    float* __restrict__ h2, float* __restrict__ asrc2, float* __restrict__ adst2)
{
    __shared__ float Wl[HID * OUTD];       // 2560 floats
    __shared__ float xs[32 * 68];          // padded stride 68
    __shared__ float s_as[32], s_ad[32];
    const int tid = threadIdx.x;
    const int r0 = blockIdx.x * 32;

    const float4* W4 = (const float4*)W2;  // 640 float4
    float4* Wl4 = (float4*)Wl;
    for (int i = tid; i < 640; i += 320) Wl4[i] = W4[i];
    const float4* x4 = (const float4*)hin;
    for (int i = tid; i < 512; i += 320) {
        int row = i >> 4;                  // 16 float4 per row
        int k4  = i & 15;
        int nr = r0 + row;
        float4 v = make_float4(0.f, 0.f, 0.f, 0.f);
        if (nr < NN) v = x4[(size_t)nr * 16 + k4];
        *(float4*)&xs[row * 68 + k4 * 4] = v;
    }
    if (tid < 32) { s_as[tid] = 0.f; s_ad[tid] = 0.f; }
    __syncthreads();

    const int r  = tid / 10;               // 0..31
    const int cg = tid % 10;
    const int c4 = cg * 4;                 // 0..36
    float a0 = 0.f, a1 = 0.f, a2 = 0.f, a3 = 0.f;
#pragma unroll 4
    for (int k4 = 0; k4 < 16; ++k4) {
        float4 xv = *(const float4*)&xs[r * 68 + k4 * 4];
        const float* wp = &Wl[(k4 * 4) * OUTD + c4];
        float4 w0 = *(const float4*)(wp);
        float4 w1 = *(const float4*)(wp + OUTD);
        float4 w2 = *(const float4*)(wp + 2 * OUTD);
        float4 w3 = *(const float4*)(wp + 3 * OUTD);
        a0 += xv.x * w0.x + xv.y * w1.x + xv.z * w2.x + xv.w * w3.x;
        a1 += xv.x * w0.y + xv.y * w1.y + xv.z * w2.y + xv.w * w3.y;
        a2 += xv.x * w0.z + xv.y * w1.z + xv.z * w2.z + xv.w * w3.z;
        a3 += xv.x * w0.w + xv.y * w1.w + xv.z * w2.w + xv.w * w3.w;
    }
    const int n = r0 + r;
    float ps = a0 * a_s[c4] + a1 * a_s[c4 + 1] + a2 * a_s[c4 + 2] + a3 * a_s[c4 + 3];
    float pd = a0 * a_d[c4] + a1 * a_d[c4 + 1] + a2 * a_d[c4 + 2] + a3 * a_d[c4 + 3];
    atomicAdd(&s_as[r], ps);
    atomicAdd(&s_ad[r], pd);
    if (n < NN) {
        float4 hv; hv.x = a0; hv.y = a1; hv.z = a2; hv.w = a3;
        *(float4*)&h2[(size_t)n * OUTD + c4] = hv;
    }
    __syncthreads();
    if (tid < 32) {
        int n2 = r0 + tid;
        if (n2 < NN) { asrc2[n2] = s_as[tid]; adst2[n2] = s_ad[tid]; }
    }
}

// ---------------------------------------------------------------- layer-2 aggregate + bias + log_softmax
__global__ __launch_bounds__(256) void k_agg2(
    const int* __restrict__ off, const int* __restrict__ esrc,
    const float* __restrict__ h2, const float* __restrict__ asrc2,
    const float* __restrict__ adst2, const float* __restrict__ b2,
    float* __restrict__ out)
{
    const int wave = threadIdx.x >> 6;
    const int lane = threadIdx.x & 63;
    const int n = blockIdx.x * 4 + wave;
    if (n >= NN) return;
    const int s0 = off[n], s1 = off[n + 1];
    const float adst = adst2[n];
    const bool act = lane < OUTD;
    float m = -INFINITY, l = 0.f, acc = 0.f;
    for (int idx = s0; idx < s1; ++idx) {
        int s = esrc[idx];
        float e = asrc2[s] + adst;
        e = (e > 0.f) ? e : 0.2f * e;
        float mn = fmaxf(m, e);
        float p = __expf(e - mn);
        float sc = __expf(m - mn);
        float hv = act ? h2[(size_t)s * OUTD + lane] : 0.f;
        l = l * sc + p;
        acc = acc * sc + p * hv;
        m = mn;
    }
    float val = act ? (acc / l + b2[lane]) : -INFINITY;
    float mx = val;
#pragma unroll
    for (int o = 32; o; o >>= 1) mx = fmaxf(mx, __shfl_xor(mx, o));
    float ex = act ? __expf(val - mx) : 0.f;
    float sm = ex;
#pragma unroll
    for (int o = 32; o; o >>= 1) sm += __shfl_xor(sm, o);
    if (act) out[(size_t)n * OUTD + lane] = val - mx - logf(sm);
}

// ----------------------------------------------------------------
extern "C" void kernel_launch(void* const* d_in, const int* in_sizes, int n_in,
                              void* d_out, int out_size, void* d_ws, size_t ws_size,
                              hipStream_t stream)
{
    const float* x   = (const float*)d_in[0];
    const int*   ei  = (const int*)  d_in[1];
    const float* W1  = (const float*)d_in[2];
    const float* as1 = (const float*)d_in[3];
    const float* ad1 = (const float*)d_in[4];
    const float* b1  = (const float*)d_in[5];
    const float* W2  = (const float*)d_in[6];
    const float* as2 = (const float*)d_in[7];
    const float* ad2 = (const float*)d_in[8];
    const float* b2  = (const float*)d_in[9];
    float* out = (float*)d_out;

    char* ws = (char*)d_ws;
    float* h1    = (float*)(ws);             // 12,800,000 B
    float* hmid  = (float*)(ws + 12800000);  // 12,800,000 B
    float* h2    = (float*)(ws + 25600000);  //  8,000,000 B
    float* asrc1 = (float*)(ws + 33600000);  //    800,000 B
    float* adst1 = (float*)(ws + 34400000);  //    800,000 B
    float* asrc2 = (float*)(ws + 35200000);  //    200,000 B
    float* adst2 = (float*)(ws + 35400000);  //    200,000 B
    int*   deg   = (int*)  (ws + 35600000);  //    200,000 B
    int*   off   = (int*)  (ws + 35800000);  //    200,016 B
    int*   cur   = (int*)  (ws + 36000016);  //    200,000 B
    int*   esrc  = (int*)  (ws + 36200016);  //  3,400,000 B

    hipLaunchKernelGGL(k_zero_deg, dim3(196),  dim3(256),  0, stream, deg);
    hipLaunchKernelGGL(k_deg,      dim3(3321), dim3(256),  0, stream, ei, deg);
    hipLaunchKernelGGL(k_scan,     dim3(1),    dim3(1024), 0, stream, deg, off, cur);
    hipLaunchKernelGGL(k_scatter,  dim3(3321), dim3(256),  0, stream, ei, cur, esrc);
    hipLaunchKernelGGL(k_gemm1,    dim3(3125), dim3(256),  0, stream, x, W1, as1, ad1, h1, asrc1, adst1);
    hipLaunchKernelGGL(k_agg1,     dim3(12500),dim3(256),  0, stream, off, esrc, h1, asrc1, adst1, b1, hmid);
    hipLaunchKernelGGL(k_gemm2,    dim3(1563), dim3(320),  0, stream, hmid, W2, as2, ad2, h2, asrc2, adst2);
    hipLaunchKernelGGL(k_agg2,     dim3(12500),dim3(256),  0, stream, off, esrc, h2, asrc2, adst2, b2, out);
}

// Round 2
// 364.115 us; speedup vs baseline: 1.3142x; 1.3142x over previous
//
#include <hip/hip_runtime.h>
#include <math.h>

#define NN    50000
#define NE0   800000
#define NE    850000
#define INDIM 128
#define HID   64
#define OUTD  40

// ---------------------------------------------------------------- CSR build
__global__ void k_zero_deg(int* __restrict__ deg) {
    int i = blockIdx.x * 256 + threadIdx.x;
    if (i < NN) deg[i] = 0;
}

__global__ void k_deg(const int* __restrict__ ei, int* __restrict__ deg) {
    int e = blockIdx.x * 256 + threadIdx.x;
    if (e >= NE) return;
    int dst = (e < NE0) ? ei[NE0 + e] : (e - NE0);
    atomicAdd(&deg[dst], 1);
}

// single-block scan: wave shuffle-scan + cross-wave LDS, 4 barriers/chunk
__global__ __launch_bounds__(1024) void k_scan(const int* __restrict__ deg,
                                               int* __restrict__ off,
                                               int* __restrict__ cur) {
    __shared__ int wsum[16];
    __shared__ int s_run;
    const int tid = threadIdx.x, wv = tid >> 6, lane = tid & 63;
    if (tid == 0) s_run = 0;
    __syncthreads();
    for (int base = 0; base < NN; base += 1024) {
        int i = base + tid;
        int v = (i < NN) ? deg[i] : 0;
        int incl = v;
#pragma unroll
        for (int s = 1; s < 64; s <<= 1) {
            int t = __shfl_up(incl, s);
            if (lane >= s) incl += t;
        }
        if (lane == 63) wsum[wv] = incl;
        __syncthreads();
        if (tid < 16) {
            int a = wsum[tid];
#pragma unroll
            for (int s = 1; s < 16; s <<= 1) {
                int t = __shfl_up(a, s);
                if (tid >= s) a += t;
            }
            wsum[tid] = a;
        }
        __syncthreads();
        int run = s_run + ((wv == 0) ? 0 : wsum[wv - 1]);
        if (i < NN) {
            int ex = run + incl - v;
            off[i] = ex;
            cur[i] = ex;
        }
        __syncthreads();               // all reads of s_run/wsum done
        if (tid == 0) s_run += wsum[15];
        __syncthreads();               // s_run visible, wsum safe to overwrite
    }
    if (tid == 0) off[NN] = NE;
}

__global__ void k_scatter(const int* __restrict__ ei, int* __restrict__ cur,
                          int* __restrict__ esrc) {
    int e = blockIdx.x * 256 + threadIdx.x;
    if (e >= NE) return;
    int src, dst;
    if (e < NE0) { src = ei[e]; dst = ei[NE0 + e]; }
    else         { src = e - NE0; dst = src; }
    int pos = atomicAdd(&cur[dst], 1);
    esrc[pos] = src;
}

// ---------------------------------------------------------------- GEMM1: x(50000x128) @ W1(128x64) + alpha logits
__global__ __launch_bounds__(256) void k_gemm1(
    const float* __restrict__ x, const float* __restrict__ W1,
    const float* __restrict__ a_s, const float* __restrict__ a_d,
    float* __restrict__ h1, float* __restrict__ asrc1, float* __restrict__ adst1)
{
    __shared__ float Wl[INDIM * HID];      // 32 KB
    __shared__ float xs[16 * 132];         // padded stride 132
    const int tid = threadIdx.x;
    const int r0 = blockIdx.x * 16;

    const float4* W4 = (const float4*)W1;
    float4* Wl4 = (float4*)Wl;
#pragma unroll
    for (int i = 0; i < 8; ++i) Wl4[tid + i * 256] = W4[tid + i * 256];

    const float4* x4 = (const float4*)x;
#pragma unroll
    for (int i = 0; i < 2; ++i) {
        int idx = tid + i * 256;           // 0..511
        int row = idx >> 5;                // 32 float4 per row
        int k4  = idx & 31;
        float4 v = x4[(size_t)(r0 + row) * 32 + k4];
        *(float4*)&xs[row * 132 + k4 * 4] = v;
    }
    __syncthreads();

    const int r  = tid >> 4;               // 0..15
    const int c4 = (tid & 15) * 4;         // 0,4,...,60
    float a0 = 0.f, a1 = 0.f, a2 = 0.f, a3 = 0.f;
#pragma unroll 8
    for (int k4 = 0; k4 < 32; ++k4) {
        float4 xv = *(const float4*)&xs[r * 132 + k4 * 4];
        const float* wp = &Wl[(k4 * 4) * HID + c4];
        float4 w0 = *(const float4*)(wp);
        float4 w1 = *(const float4*)(wp + HID);
        float4 w2 = *(const float4*)(wp + 2 * HID);
        float4 w3 = *(const float4*)(wp + 3 * HID);
        a0 += xv.x * w0.x + xv.y * w1.x + xv.z * w2.x + xv.w * w3.x;
        a1 += xv.x * w0.y + xv.y * w1.y + xv.z * w2.y + xv.w * w3.y;
        a2 += xv.x * w0.z + xv.y * w1.z + xv.z * w2.z + xv.w * w3.z;
        a3 += xv.x * w0.w + xv.y * w1.w + xv.z * w2.w + xv.w * w3.w;
    }
    const int n = r0 + r;
    float4 hv; hv.x = a0; hv.y = a1; hv.z = a2; hv.w = a3;
    *(float4*)&h1[(size_t)n * HID + c4] = hv;

    float ps = a0 * a_s[c4] + a1 * a_s[c4 + 1] + a2 * a_s[c4 + 2] + a3 * a_s[c4 + 3];
    float pd = a0 * a_d[c4] + a1 * a_d[c4 + 1] + a2 * a_d[c4 + 2] + a3 * a_d[c4 + 3];
    ps += __shfl_xor(ps, 1); ps += __shfl_xor(ps, 2);
    pd += __shfl_xor(pd, 1); pd += __shfl_xor(pd, 2);
    int cg = tid & 15;
    if ((cg & 3) == 0) {
        int head = cg >> 2;
        asrc1[n * 4 + head] = ps;
        adst1[n * 4 + head] = pd;
    }
}

// ---------------------------------------------------------------- layer-1 fused two-pass softmax + aggregate + bias + relu
// wave per node; pass1: lanes = (chunk, head); pass2: lane = output dim
__global__ __launch_bounds__(256) void k_fagg1(
    const int* __restrict__ off, const int* __restrict__ esrc,
    const float* __restrict__ h1, const float* __restrict__ asrc1,
    const float* __restrict__ adst1, const float* __restrict__ b1,
    float* __restrict__ hmid)
{
    const int wv = threadIdx.x >> 6, lane = threadIdx.x & 63;
    const int n = blockIdx.x * 4 + wv;
    if (n >= NN) return;
    const int s0 = off[n], s1 = off[n + 1];

    // ---- pass 1: (m, l) per head; lane k -> head k&3, edge-chunk k>>2
    const int hp1 = lane & 3;
    const float adst = adst1[n * 4 + hp1];
    float m = -1e30f, l = 0.f;
    for (int idx = s0 + (lane >> 2); idx < s1; idx += 16) {
        int s = esrc[idx];
        float e = asrc1[s * 4 + hp1] + adst;
        e = (e > 0.f) ? e : 0.2f * e;
        float mn = fmaxf(m, e);
        l = l * __expf(m - mn) + __expf(e - mn);
        m = mn;
    }
#pragma unroll
    for (int o = 4; o < 64; o <<= 1) {   // merge 16 chunks per head
        float m2 = __shfl_xor(m, o), l2 = __shfl_xor(l, o);
        float mn = fmaxf(m, m2);
        l = l * __expf(m - mn) + l2 * __expf(m2 - mn);
        m = mn;
    }
    // ---- redistribute to pass-2 mapping: lane = dim, head = lane>>4
    const int hp2 = lane >> 4;
    const float mh   = __shfl(m, hp2);
    const float linv = 1.f / __shfl(l, hp2);
    const float ad2  = __shfl(adst, hp2);

    // ---- pass 2: pure gather+fma, unroll 4 (no loop-carried exp chain)
    float acc = 0.f;
    int idx = s0;
    for (; idx + 3 < s1; idx += 4) {
        int sA = esrc[idx], sB = esrc[idx + 1], sC = esrc[idx + 2], sD = esrc[idx + 3];
        float eA = asrc1[sA * 4 + hp2] + ad2;
        float eB = asrc1[sB * 4 + hp2] + ad2;
        float eC = asrc1[sC * 4 + hp2] + ad2;
        float eD = asrc1[sD * 4 + hp2] + ad2;
        eA = (eA > 0.f) ? eA : 0.2f * eA;
        eB = (eB > 0.f) ? eB : 0.2f * eB;
        eC = (eC > 0.f) ? eC : 0.2f * eC;
        eD = (eD > 0.f) ? eD : 0.2f * eD;
        float hA = h1[(size_t)sA * HID + lane];
        float hB = h1[(size_t)sB * HID + lane];
        float hC = h1[(size_t)sC * HID + lane];
        float hD = h1[(size_t)sD * HID + lane];
        acc += __expf(eA - mh) * hA;
        acc += __expf(eB - mh) * hB;
        acc += __expf(eC - mh) * hC;
        acc += __expf(eD - mh) * hD;
    }
    for (; idx < s1; ++idx) {
        int s = esrc[idx];
        float e = asrc1[s * 4 + hp2] + ad2;
        e = (e > 0.f) ? e : 0.2f * e;
        acc += __expf(e - mh) * h1[(size_t)s * HID + lane];
    }
    float val = acc * linv + b1[lane];
    hmid[(size_t)n * HID + lane] = fmaxf(val, 0.f);
}

// ---------------------------------------------------------------- GEMM2: hmid(50000x64) @ W2(64x40) + alpha logits
__global__ __launch_bounds__(320) void k_gemm2(
    const float* __restrict__ hin, const float* __restrict__ W2,
    const float* __restrict__ a_s, const float* __restrict__ a_d,
    float* __restrict__ h2, float* __restrict__ asrc2, float* __restrict__ adst2)
{
    __shared__ float Wl[HID * OUTD];       // 2560 floats
    __shared__ float xs[32 * 68];          // padded stride 68
    __shared__ float s_as[32], s_ad[32];
    const int tid = threadIdx.x;
    const int r0 = blockIdx.x * 32;

    const float4* W4 = (const float4*)W2;  // 640 float4
    float4* Wl4 = (float4*)Wl;
    for (int i = tid; i < 640; i += 320) Wl4[i] = W4[i];
    const float4* x4 = (const float4*)hin;
    for (int i = tid; i < 512; i += 320) {
        int row = i >> 4;                  // 16 float4 per row
        int k4  = i & 15;
        int nr = r0 + row;
        float4 v = make_float4(0.f, 0.f, 0.f, 0.f);
        if (nr < NN) v = x4[(size_t)nr * 16 + k4];
        *(float4*)&xs[row * 68 + k4 * 4] = v;
    }
    if (tid < 32) { s_as[tid] = 0.f; s_ad[tid] = 0.f; }
    __syncthreads();

    const int r  = tid / 10;               // 0..31
    const int cg = tid % 10;
    const int c4 = cg * 4;                 // 0..36
    float a0 = 0.f, a1 = 0.f, a2 = 0.f, a3 = 0.f;
#pragma unroll 4
    for (int k4 = 0; k4 < 16; ++k4) {
        float4 xv = *(const float4*)&xs[r * 68 + k4 * 4];
        const float* wp = &Wl[(k4 * 4) * OUTD + c4];
        float4 w0 = *(const float4*)(wp);
        float4 w1 = *(const float4*)(wp + OUTD);
        float4 w2 = *(const float4*)(wp + 2 * OUTD);
        float4 w3 = *(const float4*)(wp + 3 * OUTD);
        a0 += xv.x * w0.x + xv.y * w1.x + xv.z * w2.x + xv.w * w3.x;
        a1 += xv.x * w0.y + xv.y * w1.y + xv.z * w2.y + xv.w * w3.y;
        a2 += xv.x * w0.z + xv.y * w1.z + xv.z * w2.z + xv.w * w3.z;
        a3 += xv.x * w0.w + xv.y * w1.w + xv.z * w2.w + xv.w * w3.w;
    }
    const int n = r0 + r;
    float ps = a0 * a_s[c4] + a1 * a_s[c4 + 1] + a2 * a_s[c4 + 2] + a3 * a_s[c4 + 3];
    float pd = a0 * a_d[c4] + a1 * a_d[c4 + 1] + a2 * a_d[c4 + 2] + a3 * a_d[c4 + 3];
    atomicAdd(&s_as[r], ps);
    atomicAdd(&s_ad[r], pd);
    if (n < NN) {
        float4 hv; hv.x = a0; hv.y = a1; hv.z = a2; hv.w = a3;
        *(float4*)&h2[(size_t)n * OUTD + c4] = hv;
    }
    __syncthreads();
    if (tid < 32) {
        int n2 = r0 + tid;
        if (n2 < NN) { asrc2[n2] = s_as[tid]; adst2[n2] = s_ad[tid]; }
    }
}

// ---------------------------------------------------------------- layer-2 fused two-pass softmax + aggregate + bias + log_softmax
__global__ __launch_bounds__(256) void k_fagg2(
    const int* __restrict__ off, const int* __restrict__ esrc,
    const float* __restrict__ h2, const float* __restrict__ asrc2,
    const float* __restrict__ adst2, const float* __restrict__ b2,
    float* __restrict__ out)
{
    const int wv = threadIdx.x >> 6, lane = threadIdx.x & 63;
    const int n = blockIdx.x * 4 + wv;
    if (n >= NN) return;
    const int s0 = off[n], s1 = off[n + 1];
    const float adst = adst2[n];

    // ---- pass 1: (m,l) across all 64 lanes
    float m = -1e30f, l = 0.f;
    for (int idx = s0 + lane; idx < s1; idx += 64) {
        int s = esrc[idx];
        float e = asrc2[s] + adst;
        e = (e > 0.f) ? e : 0.2f * e;
        float mn = fmaxf(m, e);
        l = l * __expf(m - mn) + __expf(e - mn);
        m = mn;
    }
#pragma unroll
    for (int o = 1; o < 64; o <<= 1) {
        float m2 = __shfl_xor(m, o), l2 = __shfl_xor(l, o);
        float mn = fmaxf(m, m2);
        l = l * __expf(m - mn) + l2 * __expf(m2 - mn);
        m = mn;
    }
    const float linv = 1.f / l;

    // ---- pass 2: gather+fma, unroll 4
    const bool act = lane < OUTD;
    float acc = 0.f;
    int idx = s0;
    for (; idx + 3 < s1; idx += 4) {
        int sA = esrc[idx], sB = esrc[idx + 1], sC = esrc[idx + 2], sD = esrc[idx + 3];
        float eA = asrc2[sA] + adst, eB = asrc2[sB] + adst;
        float eC = asrc2[sC] + adst, eD = asrc2[sD] + adst;
        eA = (eA > 0.f) ? eA : 0.2f * eA;
        eB = (eB > 0.f) ? eB : 0.2f * eB;
        eC = (eC > 0.f) ? eC : 0.2f * eC;
        eD = (eD > 0.f) ? eD : 0.2f * eD;
        float hA = act ? h2[(size_t)sA * OUTD + lane] : 0.f;
        float hB = act ? h2[(size_t)sB * OUTD + lane] : 0.f;
        float hC = act ? h2[(size_t)sC * OUTD + lane] : 0.f;
        float hD = act ? h2[(size_t)sD * OUTD + lane] : 0.f;
        acc += __expf(eA - m) * hA;
        acc += __expf(eB - m) * hB;
        acc += __expf(eC - m) * hC;
        acc += __expf(eD - m) * hD;
    }
    for (; idx < s1; ++idx) {
        int s = esrc[idx];
        float e = asrc2[s] + adst;
        e = (e > 0.f) ? e : 0.2f * e;
        float hv = act ? h2[(size_t)s * OUTD + lane] : 0.f;
        acc += __expf(e - m) * hv;
    }

    // ---- bias + log_softmax over 40 dims
    float val = act ? (acc * linv + b2[lane]) : -1e30f;
    float mx = val;
#pragma unroll
    for (int o = 32; o; o >>= 1) mx = fmaxf(mx, __shfl_xor(mx, o));
    float ex = act ? __expf(val - mx) : 0.f;
    float sm = ex;
#pragma unroll
    for (int o = 32; o; o >>= 1) sm += __shfl_xor(sm, o);
    if (act) out[(size_t)n * OUTD + lane] = val - mx - __logf(sm);
}

// ----------------------------------------------------------------
extern "C" void kernel_launch(void* const* d_in, const int* in_sizes, int n_in,
                              void* d_out, int out_size, void* d_ws, size_t ws_size,
                              hipStream_t stream)
{
    const float* x   = (const float*)d_in[0];
    const int*   ei  = (const int*)  d_in[1];
    const float* W1  = (const float*)d_in[2];
    const float* as1 = (const float*)d_in[3];
    const float* ad1 = (const float*)d_in[4];
    const float* b1  = (const float*)d_in[5];
    const float* W2  = (const float*)d_in[6];
    const float* as2 = (const float*)d_in[7];
    const float* ad2 = (const float*)d_in[8];
    const float* b2  = (const float*)d_in[9];
    float* out = (float*)d_out;

    char* ws = (char*)d_ws;
    float* h1    = (float*)(ws);             // 12,800,000 B
    float* hmid  = (float*)(ws + 12800000);  // 12,800,000 B
    float* h2    = (float*)(ws + 25600000);  //  8,000,000 B
    float* asrc1 = (float*)(ws + 33600000);  //    800,000 B
    float* adst1 = (float*)(ws + 34400000);  //    800,000 B
    float* asrc2 = (float*)(ws + 35200000);  //    200,000 B
    float* adst2 = (float*)(ws + 35400000);  //    200,000 B
    int*   deg   = (int*)  (ws + 35600000);  //    200,000 B
    int*   off   = (int*)  (ws + 35800000);  //    200,016 B
    int*   cur   = (int*)  (ws + 36000016);  //    200,000 B
    int*   esrc  = (int*)  (ws + 36200016);  //  3,400,000 B

    hipLaunchKernelGGL(k_zero_deg, dim3(196),  dim3(256),  0, stream, deg);
    hipLaunchKernelGGL(k_deg,      dim3(3321), dim3(256),  0, stream, ei, deg);
    hipLaunchKernelGGL(k_scan,     dim3(1),    dim3(1024), 0, stream, deg, off, cur);
    hipLaunchKernelGGL(k_scatter,  dim3(3321), dim3(256),  0, stream, ei, cur, esrc);
    hipLaunchKernelGGL(k_gemm1,    dim3(3125), dim3(256),  0, stream, x, W1, as1, ad1, h1, asrc1, adst1);
    hipLaunchKernelGGL(k_fagg1,    dim3(12500),dim3(256),  0, stream, off, esrc, h1, asrc1, adst1, b1, hmid);
    hipLaunchKernelGGL(k_gemm2,    dim3(1563), dim3(320),  0, stream, hmid, W2, as2, ad2, h2, asrc2, adst2);
    hipLaunchKernelGGL(k_fagg2,    dim3(12500),dim3(256),  0, stream, off, esrc, h2, asrc2, adst2, b2, out);
}

// Round 3
// 252.085 us; speedup vs baseline: 1.8983x; 1.4444x over previous
//
#include <hip/hip_runtime.h>
#include <math.h>

#define NN    50000
#define NE0   800000
#define NE    850000
#define INDIM 128
#define HID   64
#define OUTD  40

#define NB    391          // ceil(50000/128) buckets of 128 dsts
#define BSH   7            // bucket shift (dst >> 7)

// ---------------------------------------------------------------- CSR build (two-level binned)
__global__ __launch_bounds__(512) void k_bzero(int* __restrict__ bhist) {
    int i = threadIdx.x;
    if (i < NB) bhist[i] = 0;
}

// bucket histogram: LDS pre-aggregated, 256 blocks
__global__ __launch_bounds__(256) void k_hist(const int* __restrict__ ei,
                                              int* __restrict__ bhist) {
    __shared__ int lh[NB];
    const int tid = threadIdx.x;
    for (int i = tid; i < NB; i += 256) lh[i] = 0;
    __syncthreads();
    for (int e = blockIdx.x * 256 + tid; e < NE; e += 256 * 256) {
        int dst = (e < NE0) ? ei[NE0 + e] : (e - NE0);
        atomicAdd(&lh[dst >> BSH], 1);
    }
    __syncthreads();
    for (int i = tid; i < NB; i += 256)
        if (lh[i]) atomicAdd(&bhist[i], lh[i]);
}

// scan 391 buckets -> bbase[0..NB], bcur copy
__global__ __launch_bounds__(512) void k_bscan(const int* __restrict__ bhist,
                                               int* __restrict__ bbase,
                                               int* __restrict__ bcur) {
    __shared__ int wsum[8];
    const int tid = threadIdx.x, wv = tid >> 6, lane = tid & 63;
    int v = (tid < NB) ? bhist[tid] : 0;
    int incl = v;
#pragma unroll
    for (int s = 1; s < 64; s <<= 1) {
        int t = __shfl_up(incl, s);
        if (lane >= s) incl += t;
    }
    if (lane == 63) wsum[wv] = incl;
    __syncthreads();
    if (tid < 8) {
        int a = wsum[tid];
#pragma unroll
        for (int s = 1; s < 8; s <<= 1) {
            int t = __shfl_up(a, s);
            if (tid >= s) a += t;
        }
        wsum[tid] = a;
    }
    __syncthreads();
    int excl = ((wv == 0) ? 0 : wsum[wv - 1]) + incl - v;
    if (tid <= NB) bbase[tid] = excl;
    if (tid < NB)  bcur[tid]  = excl;
}

// bin edges by bucket: block reserves per-bucket ranges, writes grouped runs
__global__ __launch_bounds__(256) void k_bin(const int* __restrict__ ei,
                                             int* __restrict__ bcur,
                                             unsigned int* __restrict__ epack) {
    __shared__ int lh[NB];
    __shared__ int lbase[NB];
    const int tid = threadIdx.x;
    const int CH = (NE + 255) / 256;           // 3321
    const int e_begin = blockIdx.x * CH;
    const int e_end = (e_begin + CH < NE) ? e_begin + CH : NE;

    for (int i = tid; i < NB; i += 256) lh[i] = 0;
    __syncthreads();
    for (int e = e_begin + tid; e < e_end; e += 256) {
        int dst = (e < NE0) ? ei[NE0 + e] : (e - NE0);
        atomicAdd(&lh[dst >> BSH], 1);
    }
    __syncthreads();
    for (int i = tid; i < NB; i += 256) {
        int c = lh[i];
        lbase[i] = c ? atomicAdd(&bcur[i], c) : 0;
        lh[i] = 0;
    }
    __syncthreads();
    for (int e = e_begin + tid; e < e_end; e += 256) {
        int src, dst;
        if (e < NE0) { src = ei[e]; dst = ei[NE0 + e]; }
        else         { src = e - NE0; dst = src; }
        int bkt = dst >> BSH;
        int lpos = atomicAdd(&lh[bkt], 1);
        epack[lbase[bkt] + lpos] = (unsigned int)src | ((unsigned int)(dst & 127) << 16);
    }
}

// per-bucket fine CSR: LDS histogram over 128 dsts, scan, scatter (L2-local)
__global__ __launch_bounds__(256) void k_bucket_csr(
    const int* __restrict__ bbase, const unsigned int* __restrict__ epack,
    int* __restrict__ off, int* __restrict__ esrc) {
    __shared__ int lh[128];
    __shared__ int lcur[128];
    __shared__ int sblk;
    const int tid = threadIdx.x, lane = tid & 63;
    const int b = blockIdx.x;
    const int e0 = bbase[b], e1 = bbase[b + 1];
    const int cnt = e1 - e0;

    if (tid < 128) lh[tid] = 0;
    __syncthreads();
    for (int i = tid; i < cnt; i += 256)
        atomicAdd(&lh[epack[e0 + i] >> 16], 1);
    __syncthreads();

    int v = 0, incl = 0;
    if (tid < 128) {
        v = lh[tid];
        incl = v;
#pragma unroll
        for (int s = 1; s < 64; s <<= 1) {
            int t = __shfl_up(incl, s);
            if (lane >= s) incl += t;
        }
    }
    if (tid == 63) sblk = incl;
    __syncthreads();
    if (tid >= 64 && tid < 128) incl += sblk;
    if (tid < 128) {
        int ex = e0 + incl - v;
        lcur[tid] = ex;
        int gd = b * 128 + tid;
        if (gd < NN) off[gd] = ex;
    }
    if (b == 0 && tid == 0) off[NN] = NE;
    __syncthreads();

    for (int i = tid; i < cnt; i += 256) {
        unsigned int p = epack[e0 + i];
        int pos = atomicAdd(&lcur[p >> 16], 1);
        esrc[pos] = (int)(p & 0xFFFFu);
    }
}

// ---------------------------------------------------------------- GEMM1: x(50000x128) @ W1(128x64) + alpha logits
__global__ __launch_bounds__(256) void k_gemm1(
    const float* __restrict__ x, const float* __restrict__ W1,
    const float* __restrict__ a_s, const float* __restrict__ a_d,
    float* __restrict__ h1, float* __restrict__ asrc1, float* __restrict__ adst1)
{
    __shared__ float Wl[INDIM * HID];      // 32 KB
    __shared__ float xs[16 * 132];         // padded stride 132
    const int tid = threadIdx.x;
    const int r0 = blockIdx.x * 16;

    const float4* W4 = (const float4*)W1;
    float4* Wl4 = (float4*)Wl;
#pragma unroll
    for (int i = 0; i < 8; ++i) Wl4[tid + i * 256] = W4[tid + i * 256];

    const float4* x4 = (const float4*)x;
#pragma unroll
    for (int i = 0; i < 2; ++i) {
        int idx = tid + i * 256;           // 0..511
        int row = idx >> 5;                // 32 float4 per row
        int k4  = idx & 31;
        float4 v = x4[(size_t)(r0 + row) * 32 + k4];
        *(float4*)&xs[row * 132 + k4 * 4] = v;
    }
    __syncthreads();

    const int r  = tid >> 4;               // 0..15
    const int c4 = (tid & 15) * 4;         // 0,4,...,60
    float a0 = 0.f, a1 = 0.f, a2 = 0.f, a3 = 0.f;
#pragma unroll 8
    for (int k4 = 0; k4 < 32; ++k4) {
        float4 xv = *(const float4*)&xs[r * 132 + k4 * 4];
        const float* wp = &Wl[(k4 * 4) * HID + c4];
        float4 w0 = *(const float4*)(wp);
        float4 w1 = *(const float4*)(wp + HID);
        float4 w2 = *(const float4*)(wp + 2 * HID);
        float4 w3 = *(const float4*)(wp + 3 * HID);
        a0 += xv.x * w0.x + xv.y * w1.x + xv.z * w2.x + xv.w * w3.x;
        a1 += xv.x * w0.y + xv.y * w1.y + xv.z * w2.y + xv.w * w3.y;
        a2 += xv.x * w0.z + xv.y * w1.z + xv.z * w2.z + xv.w * w3.z;
        a3 += xv.x * w0.w + xv.y * w1.w + xv.z * w2.w + xv.w * w3.w;
    }
    const int n = r0 + r;
    float4 hv; hv.x = a0; hv.y = a1; hv.z = a2; hv.w = a3;
    *(float4*)&h1[(size_t)n * HID + c4] = hv;

    float ps = a0 * a_s[c4] + a1 * a_s[c4 + 1] + a2 * a_s[c4 + 2] + a3 * a_s[c4 + 3];
    float pd = a0 * a_d[c4] + a1 * a_d[c4 + 1] + a2 * a_d[c4 + 2] + a3 * a_d[c4 + 3];
    ps += __shfl_xor(ps, 1); ps += __shfl_xor(ps, 2);
    pd += __shfl_xor(pd, 1); pd += __shfl_xor(pd, 2);
    int cg = tid & 15;
    if ((cg & 3) == 0) {
        int head = cg >> 2;
        asrc1[n * 4 + head] = ps;
        adst1[n * 4 + head] = pd;
    }
}

// ---------------------------------------------------------------- layer-1 single-pass aggregate (no max-shift) + bias + relu
__global__ __launch_bounds__(256) void k_fagg1(
    const int* __restrict__ off, const int* __restrict__ esrc,
    const float* __restrict__ h1, const float* __restrict__ asrc1,
    const float* __restrict__ adst1, const float* __restrict__ b1,
    float* __restrict__ hmid)
{
    const int wv = threadIdx.x >> 6, lane = threadIdx.x & 63;
    const int n = blockIdx.x * 4 + wv;
    if (n >= NN) return;
    const int s0 = off[n], s1 = off[n + 1];
    const int hp = lane >> 4;
    const float adst = adst1[n * 4 + hp];

    float l = 0.f, acc = 0.f;
    int idx = s0;
    for (; idx + 3 < s1; idx += 4) {
        int sA = esrc[idx], sB = esrc[idx + 1], sC = esrc[idx + 2], sD = esrc[idx + 3];
        float eA = asrc1[sA * 4 + hp] + adst;
        float eB = asrc1[sB * 4 + hp] + adst;
        float eC = asrc1[sC * 4 + hp] + adst;
        float eD = asrc1[sD * 4 + hp] + adst;
        eA = (eA > 0.f) ? eA : 0.2f * eA;
        eB = (eB > 0.f) ? eB : 0.2f * eB;
        eC = (eC > 0.f) ? eC : 0.2f * eC;
        eD = (eD > 0.f) ? eD : 0.2f * eD;
        float hA = h1[(size_t)sA * HID + lane];
        float hB = h1[(size_t)sB * HID + lane];
        float hC = h1[(size_t)sC * HID + lane];
        float hD = h1[(size_t)sD * HID + lane];
        float wA = __expf(eA), wB = __expf(eB), wC = __expf(eC), wD = __expf(eD);
        l += wA + wB + wC + wD;
        acc += wA * hA + wB * hB + wC * hC + wD * hD;
    }
    for (; idx < s1; ++idx) {
        int s = esrc[idx];
        float e = asrc1[s * 4 + hp] + adst;
        e = (e > 0.f) ? e : 0.2f * e;
        float w = __expf(e);
        l += w;
        acc += w * h1[(size_t)s * HID + lane];
    }
    float val = acc / l + b1[lane];
    hmid[(size_t)n * HID + lane] = fmaxf(val, 0.f);
}

// ---------------------------------------------------------------- GEMM2: hmid(50000x64) @ W2(64x40) + alpha logits
__global__ __launch_bounds__(320) void k_gemm2(
    const float* __restrict__ hin, const float* __restrict__ W2,
    const float* __restrict__ a_s, const float* __restrict__ a_d,
    float* __restrict__ h2, float* __restrict__ asrc2, float* __restrict__ adst2)
{
    __shared__ float Wl[HID * OUTD];       // 2560 floats
    __shared__ float xs[32 * 68];          // padded stride 68
    __shared__ float s_as[32], s_ad[32];
    const int tid = threadIdx.x;
    const int r0 = blockIdx.x * 32;

    const float4* W4 = (const float4*)W2;  // 640 float4
    float4* Wl4 = (float4*)Wl;
    for (int i = tid; i < 640; i += 320) Wl4[i] = W4[i];
    const float4* x4 = (const float4*)hin;
    for (int i = tid; i < 512; i += 320) {
        int row = i >> 4;                  // 16 float4 per row
        int k4  = i & 15;
        int nr = r0 + row;
        float4 v = make_float4(0.f, 0.f, 0.f, 0.f);
        if (nr < NN) v = x4[(size_t)nr * 16 + k4];
        *(float4*)&xs[row * 68 + k4 * 4] = v;
    }
    if (tid < 32) { s_as[tid] = 0.f; s_ad[tid] = 0.f; }
    __syncthreads();

    const int r  = tid / 10;               // 0..31
    const int cg = tid % 10;
    const int c4 = cg * 4;                 // 0..36
    float a0 = 0.f, a1 = 0.f, a2 = 0.f, a3 = 0.f;
#pragma unroll 4
    for (int k4 = 0; k4 < 16; ++k4) {
        float4 xv = *(const float4*)&xs[r * 68 + k4 * 4];
        const float* wp = &Wl[(k4 * 4) * OUTD + c4];
        float4 w0 = *(const float4*)(wp);
        float4 w1 = *(const float4*)(wp + OUTD);
        float4 w2 = *(const float4*)(wp + 2 * OUTD);
        float4 w3 = *(const float4*)(wp + 3 * OUTD);
        a0 += xv.x * w0.x + xv.y * w1.x + xv.z * w2.x + xv.w * w3.x;
        a1 += xv.x * w0.y + xv.y * w1.y + xv.z * w2.y + xv.w * w3.y;
        a2 += xv.x * w0.z + xv.y * w1.z + xv.z * w2.z + xv.w * w3.z;
        a3 += xv.x * w0.w + xv.y * w1.w + xv.z * w2.w + xv.w * w3.w;
    }
    const int n = r0 + r;
    float ps = a0 * a_s[c4] + a1 * a_s[c4 + 1] + a2 * a_s[c4 + 2] + a3 * a_s[c4 + 3];
    float pd = a0 * a_d[c4] + a1 * a_d[c4 + 1] + a2 * a_d[c4 + 2] + a3 * a_d[c4 + 3];
    atomicAdd(&s_as[r], ps);
    atomicAdd(&s_ad[r], pd);
    if (n < NN) {
        float4 hv; hv.x = a0; hv.y = a1; hv.z = a2; hv.w = a3;
        *(float4*)&h2[(size_t)n * OUTD + c4] = hv;
    }
    __syncthreads();
    if (tid < 32) {
        int n2 = r0 + tid;
        if (n2 < NN) { asrc2[n2] = s_as[tid]; adst2[n2] = s_ad[tid]; }
    }
}

// ---------------------------------------------------------------- layer-2 single-pass aggregate + bias + log_softmax
__global__ __launch_bounds__(256) void k_fagg2(
    const int* __restrict__ off, const int* __restrict__ esrc,
    const float* __restrict__ h2, const float* __restrict__ asrc2,
    const float* __restrict__ adst2, const float* __restrict__ b2,
    float* __restrict__ out)
{
    const int wv = threadIdx.x >> 6, lane = threadIdx.x & 63;
    const int n = blockIdx.x * 4 + wv;
    if (n >= NN) return;
    const int s0 = off[n], s1 = off[n + 1];
    const float adst = adst2[n];
    const bool act = lane < OUTD;

    float l = 0.f, acc = 0.f;
    int idx = s0;
    for (; idx + 3 < s1; idx += 4) {
        int sA = esrc[idx], sB = esrc[idx + 1], sC = esrc[idx + 2], sD = esrc[idx + 3];
        float eA = asrc2[sA] + adst, eB = asrc2[sB] + adst;
        float eC = asrc2[sC] + adst, eD = asrc2[sD] + adst;
        eA = (eA > 0.f) ? eA : 0.2f * eA;
        eB = (eB > 0.f) ? eB : 0.2f * eB;
        eC = (eC > 0.f) ? eC : 0.2f * eC;
        eD = (eD > 0.f) ? eD : 0.2f * eD;
        float hA = act ? h2[(size_t)sA * OUTD + lane] : 0.f;
        float hB = act ? h2[(size_t)sB * OUTD + lane] : 0.f;
        float hC = act ? h2[(size_t)sC * OUTD + lane] : 0.f;
        float hD = act ? h2[(size_t)sD * OUTD + lane] : 0.f;
        float wA = __expf(eA), wB = __expf(eB), wC = __expf(eC), wD = __expf(eD);
        l += wA + wB + wC + wD;
        acc += wA * hA + wB * hB + wC * hC + wD * hD;
    }
    for (; idx < s1; ++idx) {
        int s = esrc[idx];
        float e = asrc2[s] + adst;
        e = (e > 0.f) ? e : 0.2f * e;
        float w = __expf(e);
        float hv = act ? h2[(size_t)s * OUTD + lane] : 0.f;
        l += w;
        acc += w * hv;
    }

    float val = act ? (acc / l + b2[lane]) : -1e30f;
    float mx = val;
#pragma unroll
    for (int o = 32; o; o >>= 1) mx = fmaxf(mx, __shfl_xor(mx, o));
    float ex = act ? __expf(val - mx) : 0.f;
    float sm = ex;
#pragma unroll
    for (int o = 32; o; o >>= 1) sm += __shfl_xor(sm, o);
    if (act) out[(size_t)n * OUTD + lane] = val - mx - __logf(sm);
}

// ----------------------------------------------------------------
extern "C" void kernel_launch(void* const* d_in, const int* in_sizes, int n_in,
                              void* d_out, int out_size, void* d_ws, size_t ws_size,
                              hipStream_t stream)
{
    const float* x   = (const float*)d_in[0];
    const int*   ei  = (const int*)  d_in[1];
    const float* W1  = (const float*)d_in[2];
    const float* as1 = (const float*)d_in[3];
    const float* ad1 = (const float*)d_in[4];
    const float* b1  = (const float*)d_in[5];
    const float* W2  = (const float*)d_in[6];
    const float* as2 = (const float*)d_in[7];
    const float* ad2 = (const float*)d_in[8];
    const float* b2  = (const float*)d_in[9];
    float* out = (float*)d_out;

    char* ws = (char*)d_ws;
    float* h1    = (float*)(ws);             // 12,800,000 B
    float* hmid  = (float*)(ws + 12800000);  // 12,800,000 B
    float* h2    = (float*)(ws + 25600000);  //  8,000,000 B (aliases epack - epack dead before gemm2)
    unsigned int* epack = (unsigned int*)(ws + 25600000);  // 3,400,000 B
    float* asrc1 = (float*)(ws + 33600000);  //    800,000 B
    float* adst1 = (float*)(ws + 34400000);  //    800,000 B
    float* asrc2 = (float*)(ws + 35200000);  //    200,000 B
    float* adst2 = (float*)(ws + 35400000);  //    200,000 B
    int*   off   = (int*)  (ws + 35600000);  //    200,016 B
    int*   esrc  = (int*)  (ws + 35800016);  //  3,400,000 B
    int*   bhist = (int*)  (ws + 39200016);  //      1,568 B
    int*   bbase = (int*)  (ws + 39201584);  //      1,568 B
    int*   bcur  = (int*)  (ws + 39203152);  //      1,564 B

    hipLaunchKernelGGL(k_bzero,      dim3(1),    dim3(512), 0, stream, bhist);
    hipLaunchKernelGGL(k_hist,       dim3(256),  dim3(256), 0, stream, ei, bhist);
    hipLaunchKernelGGL(k_bscan,      dim3(1),    dim3(512), 0, stream, bhist, bbase, bcur);
    hipLaunchKernelGGL(k_bin,        dim3(256),  dim3(256), 0, stream, ei, bcur, epack);
    hipLaunchKernelGGL(k_bucket_csr, dim3(NB),   dim3(256), 0, stream, bbase, epack, off, esrc);
    hipLaunchKernelGGL(k_gemm1,      dim3(3125), dim3(256), 0, stream, x, W1, as1, ad1, h1, asrc1, adst1);
    hipLaunchKernelGGL(k_fagg1,      dim3(12500),dim3(256), 0, stream, off, esrc, h1, asrc1, adst1, b1, hmid);
    hipLaunchKernelGGL(k_gemm2,      dim3(1563), dim3(320), 0, stream, hmid, W2, as2, ad2, h2, asrc2, adst2);
    hipLaunchKernelGGL(k_fagg2,      dim3(12500),dim3(256), 0, stream, off, esrc, h2, asrc2, adst2, b2, out);
}